// Round 1
// baseline (192.141 us; speedup 1.0000x reference)
//
#include <hip/hip_runtime.h>

#define N_NODES 50000
#define E_EDGES 625000
#define D 128           // D_IN == D_OUT == 128

// ---------------------------------------------------------------------------
// Kernel 1: rowptr[n] = lower_bound(dst, n)  for n in [0, N]  (dst is sorted)
// ---------------------------------------------------------------------------
__global__ void rowptr_kernel(const int* __restrict__ dst, int* __restrict__ rowptr) {
    int n = blockIdx.x * blockDim.x + threadIdx.x;
    if (n > N_NODES) return;
    int lo = 0, hi = E_EDGES;
    while (lo < hi) {
        int mid = (lo + hi) >> 1;
        if (dst[mid] < n) lo = mid + 1; else hi = mid;
    }
    rowptr[n] = lo;
}

// ---------------------------------------------------------------------------
// Kernel 2: agg[n, :] = sum_{e: dst[e]==n} feat[src[e], :] * affine[e]
// 32 threads per node, each owns 4 consecutive features (float4).
// Per edge: one fully-coalesced 512B read of the source feature row.
// No atomics (CSR ranges are disjoint).
// ---------------------------------------------------------------------------
__global__ __launch_bounds__(256) void agg_kernel(const float* __restrict__ feat,
                                                  const float* __restrict__ affine,
                                                  const int* __restrict__ src,
                                                  const int* __restrict__ rowptr,
                                                  float* __restrict__ agg) {
    int tid   = threadIdx.x;           // 0..255
    int g     = tid >> 5;              // node slot within block: 0..7
    int lane4 = (tid & 31) << 2;       // feature offset: 0,4,...,124
    int n = blockIdx.x * 8 + g;
    if (n >= N_NODES) return;
    int lo = rowptr[n];
    int hi = rowptr[n + 1];
    float4 acc = {0.f, 0.f, 0.f, 0.f};
    for (int e = lo; e < hi; ++e) {
        int   s = src[e];              // broadcast within the 32-thread group
        float a = affine[e];
        const float4 f = *(const float4*)(feat + (size_t)s * D + lane4);
        acc.x += f.x * a;
        acc.y += f.y * a;
        acc.z += f.z * a;
        acc.w += f.w * a;
    }
    *(float4*)(agg + (size_t)n * D + lane4) = acc;
}

// ---------------------------------------------------------------------------
// Kernel 3: out = concat(feat, agg) @ W + b     (fp32, vector ALU)
// Block tile: 64 rows x 128 cols, BK=32 (never straddles the concat seam).
// 256 threads, each computes an 8x4 micro-tile.
// LDS: As (A transposed, 32x64 = 8KB) + Bs (32x128 = 16KB).
// ---------------------------------------------------------------------------
#define BM 64
#define BK 32

__global__ __launch_bounds__(256) void gemm_kernel(const float* __restrict__ feat,
                                                   const float* __restrict__ agg,
                                                   const float* __restrict__ W,   // [256][128]
                                                   const float* __restrict__ bias,// [128]
                                                   float* __restrict__ out) {
    __shared__ float As[BK][BM];   // A^T tile
    __shared__ float Bs[BK][D];    // W tile

    int tid = threadIdx.x;
    int m0  = blockIdx.x * BM;
    int c0  = (tid & 31) * 4;      // output cols c0..c0+3
    int r0  = (tid >> 5) * 8;      // output rows r0..r0+7 (within tile)

    float acc[8][4] = {};

    for (int k0 = 0; k0 < 2 * D; k0 += BK) {
        const float* Asrc = (k0 < D) ? (feat + k0) : (agg + (k0 - D));

        // Load A tile: 64 rows x 32 k = 512 float4s -> 2 per thread.
        #pragma unroll
        for (int i = 0; i < 2; ++i) {
            int idx = tid + i * 256;       // 0..511
            int row = idx >> 3;            // 0..63
            int kk  = (idx & 7) * 4;       // 0..28
            float4 v = {0.f, 0.f, 0.f, 0.f};
            int gm = m0 + row;
            if (gm < N_NODES) v = *(const float4*)(Asrc + (size_t)gm * D + kk);
            As[kk + 0][row] = v.x;
            As[kk + 1][row] = v.y;
            As[kk + 2][row] = v.z;
            As[kk + 3][row] = v.w;
        }
        // Load B tile: 32 rows x 128 cols = 1024 float4s -> 4 per thread.
        #pragma unroll
        for (int i = 0; i < 4; ++i) {
            int idx = tid + i * 256;       // 0..1023
            int row = idx >> 5;            // 0..31
            int cc  = (idx & 31) * 4;      // 0..124
            *(float4*)(&Bs[row][cc]) = *(const float4*)(W + (size_t)(k0 + row) * D + cc);
        }
        __syncthreads();

        #pragma unroll
        for (int k = 0; k < BK; ++k) {
            float a[8];
            #pragma unroll
            for (int i = 0; i < 8; ++i) a[i] = As[k][r0 + i];
            float4 bv = *(const float4*)(&Bs[k][c0]);
            #pragma unroll
            for (int i = 0; i < 8; ++i) {
                acc[i][0] += a[i] * bv.x;
                acc[i][1] += a[i] * bv.y;
                acc[i][2] += a[i] * bv.z;
                acc[i][3] += a[i] * bv.w;
            }
        }
        __syncthreads();
    }

    float4 bv = *(const float4*)(bias + c0);
    #pragma unroll
    for (int i = 0; i < 8; ++i) {
        int gm = m0 + r0 + i;
        if (gm < N_NODES) {
            float4 o;
            o.x = acc[i][0] + bv.x;
            o.y = acc[i][1] + bv.y;
            o.z = acc[i][2] + bv.z;
            o.w = acc[i][3] + bv.w;
            *(float4*)(out + (size_t)gm * D + c0) = o;
        }
    }
}

// ---------------------------------------------------------------------------
extern "C" void kernel_launch(void* const* d_in, const int* in_sizes, int n_in,
                              void* d_out, int out_size, void* d_ws, size_t ws_size,
                              hipStream_t stream) {
    const float* feat   = (const float*)d_in[0];   // [N,128]
    const float* affine = (const float*)d_in[1];   // [E]
    const int*   src    = (const int*)  d_in[2];   // [E]
    const int*   dst    = (const int*)  d_in[3];   // [E] sorted
    const float* W      = (const float*)d_in[4];   // [256,128]
    const float* bias   = (const float*)d_in[5];   // [128]
    float*       out    = (float*)d_out;           // [N,128]

    // Workspace layout: rowptr (N+1 ints) at 0; agg (N*128 floats) at 256KB.
    int*   rowptr = (int*)d_ws;
    float* agg    = (float*)((char*)d_ws + (256u * 1024u));

    rowptr_kernel<<<(N_NODES + 1 + 255) / 256, 256, 0, stream>>>(dst, rowptr);
    agg_kernel<<<(N_NODES + 7) / 8, 256, 0, stream>>>(feat, affine, src, rowptr, agg);
    gemm_kernel<<<(N_NODES + BM - 1) / BM, 256, 0, stream>>>(feat, agg, W, bias, out);
}

// Round 2
// 175.642 us; speedup vs baseline: 1.0939x; 1.0939x over previous
//
#include <hip/hip_runtime.h>

#define N_NODES 50000
#define E_EDGES 625000
#define D 128           // D_IN == D_OUT == 128

typedef __attribute__((ext_vector_type(8))) short short8;
typedef __attribute__((ext_vector_type(4))) float float4v;

static __device__ inline unsigned short f2bf(float f) {
    union { float f; unsigned u; } v; v.f = f;
    unsigned r = v.u + 0x7FFFu + ((v.u >> 16) & 1u);   // RNE
    return (unsigned short)(r >> 16);
}

// ---------------------------------------------------------------------------
// Kernel 1: rowptr[n] = lower_bound(dst, n)  (dst sorted)
// ---------------------------------------------------------------------------
__global__ void rowptr_kernel(const int* __restrict__ dst, int* __restrict__ rowptr) {
    int n = blockIdx.x * blockDim.x + threadIdx.x;
    if (n > N_NODES) return;
    int lo = 0, hi = E_EDGES;
    while (lo < hi) {
        int mid = (lo + hi) >> 1;
        if (dst[mid] < n) lo = mid + 1; else hi = mid;
    }
    rowptr[n] = lo;
}

// ---------------------------------------------------------------------------
// Kernel 2: Z = feat @ [W1 | W2]  (bf16 MFMA, fp32 acc)
//   cols 0..127  -> out  (fp32, + bias)        [this is feat@W1 + b]
//   cols 128..255-> Y    (bf16)                [this is feat@W2]
// Block: 256 thr = 4 waves, BM=64 (16 rows/wave), full N'=256, K=128.
// W staged once into 64KB LDS as bf16, [n][k] layout with XOR chunk swizzle
// (chunk c=k/8 stored at c^(n&7)) -> 2-way bank conflicts only (free).
// A fragments loaded straight from global fp32, converted to bf16 in regs.
// ---------------------------------------------------------------------------
__global__ __launch_bounds__(256, 2) void gemm_mfma(const float* __restrict__ feat,
                                                    const float* __restrict__ W,    // [256][128]
                                                    const float* __restrict__ bias, // [128]
                                                    float* __restrict__ out,        // [N][128]
                                                    unsigned short* __restrict__ Y) // [N][128] bf16
{
    __shared__ unsigned short Bls[256 * 128];   // 64 KB

    int tid = threadIdx.x;

    // ---- stage Wc[k][n] = (n<128 ? W[k][n] : W[k+128][n-128]) into LDS ----
    #pragma unroll
    for (int i = 0; i < 32; ++i) {
        int linear = i * 256 + tid;          // 0..8191 float4s
        int k  = linear >> 6;                // 0..127
        int n0 = (linear & 63) * 4;          // 0..252
        const float* srcp = (n0 < 128) ? (W + (size_t)k * D + n0)
                                       : (W + (size_t)(k + 128) * D + (n0 - 128));
        float4 w = *(const float4*)srcp;
        float wv[4] = {w.x, w.y, w.z, w.w};
        #pragma unroll
        for (int j = 0; j < 4; ++j) {
            int n = n0 + j;
            int idx = n * 128 + ((((k >> 3) ^ (n & 7)) << 3) | (k & 7));
            Bls[idx] = f2bf(wv[j]);
        }
    }
    __syncthreads();

    int wave = tid >> 6;
    int lane = tid & 63;
    int m = lane & 15;          // A row within 16-row wave tile; also D col within tile
    int q = lane >> 4;          // quad
    int r0 = blockIdx.x * 64 + wave * 16;
    int row_a = r0 + m;
    bool valid = row_a < N_NODES;

    // ---- A fragments for all 4 k-steps (k = ks*32 + q*8 + j) ----
    short8 fa[4];
    const float* ap = feat + (size_t)row_a * D + q * 8;
    #pragma unroll
    for (int ks = 0; ks < 4; ++ks) {
        float4 u = {0.f,0.f,0.f,0.f}, v = {0.f,0.f,0.f,0.f};
        if (valid) {
            u = *(const float4*)(ap + ks * 32);
            v = *(const float4*)(ap + ks * 32 + 4);
        }
        short8 a;
        a[0] = (short)f2bf(u.x); a[1] = (short)f2bf(u.y);
        a[2] = (short)f2bf(u.z); a[3] = (short)f2bf(u.w);
        a[4] = (short)f2bf(v.x); a[5] = (short)f2bf(v.y);
        a[6] = (short)f2bf(v.z); a[7] = (short)f2bf(v.w);
        fa[ks] = a;
    }

    // ---- 16 column tiles of 16 ----
    #pragma unroll
    for (int t = 0; t < 16; ++t) {
        int n0 = t * 16;
        int nn = n0 + m;                         // B row in LDS / D col
        float4v acc = {0.f, 0.f, 0.f, 0.f};
        #pragma unroll
        for (int ks = 0; ks < 4; ++ks) {
            int c = (ks * 4 + q) ^ (m & 7);      // swizzled chunk
            short8 b = *(const short8*)(&Bls[nn * 128 + c * 8]);
            acc = __builtin_amdgcn_mfma_f32_16x16x32_bf16(fa[ks], b, acc, 0, 0, 0);
        }
        // D[row=(q*4+r)][col=m] within tile
        if (n0 < 128) {
            float bv = bias[nn];
            #pragma unroll
            for (int r = 0; r < 4; ++r) {
                int row = r0 + q * 4 + r;
                if (row < N_NODES) out[(size_t)row * D + nn] = acc[r] + bv;
            }
        } else {
            #pragma unroll
            for (int r = 0; r < 4; ++r) {
                int row = r0 + q * 4 + r;
                if (row < N_NODES) Y[(size_t)row * D + (nn - 128)] = f2bf(acc[r]);
            }
        }
    }
}

// ---------------------------------------------------------------------------
// Kernel 3: out[n,:] += sum_{e in [rowptr[n],rowptr[n+1])} affine[e]*Y[src[e],:]
// One wave per node; lane owns 2 features (one packed bf16 dword per edge).
// Edge loop unrolled x2 for MLP. No atomics (CSR ranges disjoint).
// ---------------------------------------------------------------------------
__global__ __launch_bounds__(256) void agg_add(const unsigned short* __restrict__ Y,
                                               const float* __restrict__ affine,
                                               const int* __restrict__ src,
                                               const int* __restrict__ rowptr,
                                               float* __restrict__ out) {
    int wave = threadIdx.x >> 6;
    int lane = threadIdx.x & 63;
    int n = blockIdx.x * 4 + wave;
    if (n >= N_NODES) return;
    int lo = rowptr[n], hi = rowptr[n + 1];
    int f0 = lane << 1;

    float a0 = 0.f, b0 = 0.f, a1 = 0.f, b1 = 0.f;
    int e = lo;
    for (; e + 1 < hi; e += 2) {
        int   s0 = src[e],      s1 = src[e + 1];
        float w0 = affine[e],   w1 = affine[e + 1];
        unsigned p0 = *(const unsigned*)(Y + (size_t)s0 * D + f0);
        unsigned p1 = *(const unsigned*)(Y + (size_t)s1 * D + f0);
        a0 += __uint_as_float(p0 << 16) * w0;
        b0 += __uint_as_float(p0 & 0xFFFF0000u) * w0;
        a1 += __uint_as_float(p1 << 16) * w1;
        b1 += __uint_as_float(p1 & 0xFFFF0000u) * w1;
    }
    if (e < hi) {
        int s0 = src[e]; float w0 = affine[e];
        unsigned p0 = *(const unsigned*)(Y + (size_t)s0 * D + f0);
        a0 += __uint_as_float(p0 << 16) * w0;
        b0 += __uint_as_float(p0 & 0xFFFF0000u) * w0;
    }

    float2 z = *(const float2*)(out + (size_t)n * D + f0);
    z.x += a0 + a1;
    z.y += b0 + b1;
    *(float2*)(out + (size_t)n * D + f0) = z;
}

// ---------------------------------------------------------------------------
extern "C" void kernel_launch(void* const* d_in, const int* in_sizes, int n_in,
                              void* d_out, int out_size, void* d_ws, size_t ws_size,
                              hipStream_t stream) {
    const float* feat   = (const float*)d_in[0];   // [N,128]
    const float* affine = (const float*)d_in[1];   // [E]
    const int*   src    = (const int*)  d_in[2];   // [E]
    const int*   dst    = (const int*)  d_in[3];   // [E] sorted
    const float* W      = (const float*)d_in[4];   // [256,128]
    const float* bias   = (const float*)d_in[5];   // [128]
    float*       out    = (float*)d_out;           // [N,128]

    // ws: rowptr (N+1 ints) at 0; Y (N*128 bf16 = 12.8MB) at 256KB.
    int*            rowptr = (int*)d_ws;
    unsigned short* Y      = (unsigned short*)((char*)d_ws + (256u * 1024u));

    rowptr_kernel<<<(N_NODES + 1 + 255) / 256, 256, 0, stream>>>(dst, rowptr);
    gemm_mfma<<<(N_NODES + 63) / 64, 256, 0, stream>>>(feat, W, bias, out, Y);
    agg_add<<<(N_NODES + 3) / 4, 256, 0, stream>>>(Y, affine, src, rowptr, out);
}

// Round 3
// 142.898 us; speedup vs baseline: 1.3446x; 1.2291x over previous
//
#include <hip/hip_runtime.h>

#define N_NODES 50000
#define E_EDGES 625000
#define D 128

typedef __attribute__((ext_vector_type(8)))  short  short8;
typedef __attribute__((ext_vector_type(16))) float  floatx16;

static __device__ inline unsigned short f2bf(float f) {
    union { float f; unsigned u; } v; v.f = f;
    unsigned r = v.u + 0x7FFFu + ((v.u >> 16) & 1u);   // RNE
    return (unsigned short)(r >> 16);
}
static __device__ inline float bflo(unsigned p) { return __uint_as_float(p << 16); }
static __device__ inline float bfhi(unsigned p) { return __uint_as_float(p & 0xFFFF0000u); }

// ---------------------------------------------------------------------------
// Kernel 1 (prep): rowptr via binary search on sorted dst, AND the bf16 W
// image in final LDS layout: slot t = h*2048 + c*128 + n  (short8) holds
// W[h*128 + c*8 + j][n], j=0..7.  (h=0: W1 rows 0..127; h=1: W2 rows 128..255)
// ---------------------------------------------------------------------------
__global__ __launch_bounds__(256) void prep_kernel(const int* __restrict__ dst,
                                                   const float* __restrict__ W,
                                                   int* __restrict__ rowptr,
                                                   unsigned short* __restrict__ wimg) {
    int t = blockIdx.x * 256 + threadIdx.x;
    if (t <= N_NODES) {
        int lo = 0, hi = E_EDGES;
        while (lo < hi) {
            int mid = (lo + hi) >> 1;
            if (dst[mid] < t) lo = mid + 1; else hi = mid;
        }
        rowptr[t] = lo;
    }
    if (t < 4096) {
        int n = t & 127;
        int c = (t >> 7) & 15;
        int h = t >> 11;
        int krow = h * 128 + c * 8;
        short8 v;
        #pragma unroll
        for (int j = 0; j < 8; ++j)
            v[j] = (short)f2bf(W[(size_t)(krow + j) * D + n]);
        *((short8*)wimg + t) = v;
    }
}

// ---------------------------------------------------------------------------
// Kernel 2: Z = feat @ [W1 | W2] with 32x32x16 bf16 MFMA.
// Column-split: h = blockIdx&1 selects W1 (writes out, +bias) or W2 (writes Y).
// Block: 256 thr = 4 waves x 32 rows = 128 rows. LDS 32 KB = half W image,
// staged as a stride-1 short8 copy (conflict-free). A fragments straight from
// global fp32 feat, converted in-reg.
// ---------------------------------------------------------------------------
__global__ __launch_bounds__(256, 3) void gemm_mfma(const float* __restrict__ feat,
                                                    const unsigned short* __restrict__ wimg,
                                                    const float* __restrict__ bias,
                                                    float* __restrict__ out,
                                                    unsigned short* __restrict__ Y) {
    __shared__ short8 Bls[2048];   // 32 KB: slot c*128+n

    int tid = threadIdx.x;
    int h   = blockIdx.x & 1;
    int b   = blockIdx.x >> 1;

    const short8* wsrc = (const short8*)wimg + h * 2048;
    #pragma unroll
    for (int i = 0; i < 8; ++i)
        Bls[tid + i * 256] = wsrc[tid + i * 256];

    int wave = tid >> 6;
    int lane = tid & 63;
    int m = lane & 31;          // A row within wave tile / B+D col within tile
    int g = lane >> 5;          // k-half selector
    int row0   = b * 128 + wave * 32;
    int row_a  = row0 + m;
    int rclamp = row_a < N_NODES ? row_a : 0;

    // A fragments for 8 k-steps: fa[ks][j] = feat[row][ks*16 + g*8 + j]
    short8 fa[8];
    const float* ap = feat + (size_t)rclamp * D + g * 8;
    #pragma unroll
    for (int ks = 0; ks < 8; ++ks) {
        float4 u = *(const float4*)(ap + ks * 16);
        float4 v = *(const float4*)(ap + ks * 16 + 4);
        short8 a;
        a[0] = (short)f2bf(u.x); a[1] = (short)f2bf(u.y);
        a[2] = (short)f2bf(u.z); a[3] = (short)f2bf(u.w);
        a[4] = (short)f2bf(v.x); a[5] = (short)f2bf(v.y);
        a[6] = (short)f2bf(v.z); a[7] = (short)f2bf(v.w);
        fa[ks] = a;
    }
    __syncthreads();

    #pragma unroll
    for (int t4 = 0; t4 < 4; ++t4) {
        int n = t4 * 32 + m;    // column within this half
        floatx16 acc = {0,0,0,0, 0,0,0,0, 0,0,0,0, 0,0,0,0};
        #pragma unroll
        for (int ks = 0; ks < 8; ++ks) {
            short8 bb = Bls[(ks * 2 + g) * 128 + n];
            acc = __builtin_amdgcn_mfma_f32_32x32x16_bf16(fa[ks], bb, acc, 0, 0, 0);
        }
        // D layout: col = lane&31, row = (reg&3) + 8*(reg>>2) + 4*g
        if (h == 0) {
            float bv = bias[n];
            #pragma unroll
            for (int r = 0; r < 16; ++r) {
                int row = row0 + (r & 3) + 8 * (r >> 2) + 4 * g;
                if (row < N_NODES) out[(size_t)row * D + n] = acc[r] + bv;
            }
        } else {
            #pragma unroll
            for (int r = 0; r < 16; ++r) {
                int row = row0 + (r & 3) + 8 * (r >> 2) + 4 * g;
                if (row < N_NODES) Y[(size_t)row * D + n] = f2bf(acc[r]);
            }
        }
    }
}

// ---------------------------------------------------------------------------
// Kernel 3: out[n,:] += sum_e affine[e] * Y[src[e],:]
// One wave per node. Half-wave edge pairing: lanes g=lane>>5 own edge parity,
// j=lane&31 owns 4 features (8 B bf16). Unroll x2 -> 4 edges in flight.
// Cross-half reduce via __shfl_xor(.,32); half-wave float4 RMW on out.
// ---------------------------------------------------------------------------
__global__ __launch_bounds__(256) void agg_add(const unsigned short* __restrict__ Y,
                                               const float* __restrict__ affine,
                                               const int* __restrict__ src,
                                               const int* __restrict__ rowptr,
                                               float* __restrict__ out) {
    int wave = threadIdx.x >> 6;
    int lane = threadIdx.x & 63;
    int n = blockIdx.x * 4 + wave;
    if (n >= N_NODES) return;
    int lo = rowptr[n], hi = rowptr[n + 1];
    int g = lane >> 5;
    int j4 = (lane & 31) << 2;          // feature offset (ushorts)

    float a0 = 0.f, a1 = 0.f, a2 = 0.f, a3 = 0.f;   // edge-set 0
    float b0 = 0.f, b1 = 0.f, b2 = 0.f, b3 = 0.f;   // edge-set 1

    int e = lo;
    for (; e + 4 <= hi; e += 4) {
        int   i0 = e + g,      i1 = e + 2 + g;
        int   s0 = src[i0];    float w0 = affine[i0];
        int   s1 = src[i1];    float w1 = affine[i1];
        uint2 p0 = *(const uint2*)(Y + (size_t)s0 * D + j4);
        uint2 p1 = *(const uint2*)(Y + (size_t)s1 * D + j4);
        a0 += bflo(p0.x) * w0;  a1 += bfhi(p0.x) * w0;
        a2 += bflo(p0.y) * w0;  a3 += bfhi(p0.y) * w0;
        b0 += bflo(p1.x) * w1;  b1 += bfhi(p1.x) * w1;
        b2 += bflo(p1.y) * w1;  b3 += bfhi(p1.y) * w1;
    }
    for (; e < hi; e += 2) {            // tail: up to 3 edges, predicated pairs
        int  i = e + g;
        bool valid = i < hi;
        int   s = src[valid ? i : hi - 1];
        float w = valid ? affine[i] : 0.f;
        uint2 p = *(const uint2*)(Y + (size_t)s * D + j4);
        a0 += bflo(p.x) * w;  a1 += bfhi(p.x) * w;
        a2 += bflo(p.y) * w;  a3 += bfhi(p.y) * w;
    }

    float r0 = a0 + b0, r1 = a1 + b1, r2 = a2 + b2, r3 = a3 + b3;
    r0 += __shfl_xor(r0, 32);
    r1 += __shfl_xor(r1, 32);
    r2 += __shfl_xor(r2, 32);
    r3 += __shfl_xor(r3, 32);

    if (g == 0) {
        float4 z = *(const float4*)(out + (size_t)n * D + j4);
        z.x += r0; z.y += r1; z.z += r2; z.w += r3;
        *(float4*)(out + (size_t)n * D + j4) = z;
    }
}

// ---------------------------------------------------------------------------
extern "C" void kernel_launch(void* const* d_in, const int* in_sizes, int n_in,
                              void* d_out, int out_size, void* d_ws, size_t ws_size,
                              hipStream_t stream) {
    const float* feat   = (const float*)d_in[0];
    const float* affine = (const float*)d_in[1];
    const int*   src    = (const int*)  d_in[2];
    const int*   dst    = (const int*)  d_in[3];
    const float* W      = (const float*)d_in[4];
    const float* bias   = (const float*)d_in[5];
    float*       out    = (float*)d_out;

    // ws: wimg (64 KB) @0; rowptr (200 KB) @64K; Y (12.8 MB bf16) @260 KB.
    unsigned short* wimg   = (unsigned short*)d_ws;
    int*            rowptr = (int*)((char*)d_ws + 65536);
    unsigned short* Y      = (unsigned short*)((char*)d_ws + 266240);

    prep_kernel<<<196, 256, 0, stream>>>(dst, W, rowptr, wimg);
    gemm_mfma<<<2 * ((N_NODES + 127) / 128), 256, 0, stream>>>(feat, wimg, bias, out, Y);
    agg_add<<<(N_NODES + 3) / 4, 256, 0, stream>>>(Y, affine, src, rowptr, out);
}

// Round 4
// 137.820 us; speedup vs baseline: 1.3941x; 1.0368x over previous
//
#include <hip/hip_runtime.h>

#define N_NODES 50000
#define E_EDGES 625000
#define D 128

typedef __attribute__((ext_vector_type(8)))  short  short8;
typedef __attribute__((ext_vector_type(16))) float  floatx16;

static __device__ inline unsigned short f2bf(float f) {
    union { float f; unsigned u; } v; v.f = f;
    unsigned r = v.u + 0x7FFFu + ((v.u >> 16) & 1u);   // RNE
    return (unsigned short)(r >> 16);
}
static __device__ inline float bflo(unsigned p) { return __uint_as_float(p << 16); }
static __device__ inline float bfhi(unsigned p) { return __uint_as_float(p & 0xFFFF0000u); }

// ---------------------------------------------------------------------------
// Kernel 1 (prep): rowptr via binary search on sorted dst, plus the bf16 W
// image in final LDS layout: slot t = h*2048 + c*128 + n (short8) holds
// W[h*128 + c*8 + j][n], j=0..7.
// ---------------------------------------------------------------------------
__global__ __launch_bounds__(256) void prep_kernel(const int* __restrict__ dst,
                                                   const float* __restrict__ W,
                                                   int* __restrict__ rowptr,
                                                   unsigned short* __restrict__ wimg) {
    int t = blockIdx.x * 256 + threadIdx.x;
    if (t <= N_NODES) {
        int lo = 0, hi = E_EDGES;
        while (lo < hi) {
            int mid = (lo + hi) >> 1;
            if (dst[mid] < t) lo = mid + 1; else hi = mid;
        }
        rowptr[t] = lo;
    }
    if (t < 4096) {
        int n = t & 127;
        int c = (t >> 7) & 15;
        int h = t >> 11;
        int krow = h * 128 + c * 8;
        short8 v;
        #pragma unroll
        for (int j = 0; j < 8; ++j)
            v[j] = (short)f2bf(W[(size_t)(krow + j) * D + n]);
        *((short8*)wimg + t) = v;
    }
}

// ---------------------------------------------------------------------------
// Kernel 2: Z = feat @ [W1 | W2] with 32x32x16 bf16 MFMA.
// h selects W1 (writes out, +bias) or W2 (writes Y bf16).
// XCD-pairing swizzle: (b,h=0) and (b,h=1) are 8 apart in blockIdx so the
// round-robin XCD mapping puts both on the same XCD -> feat rows hit L2.
// ---------------------------------------------------------------------------
#define NB_M 391   // ceil(N/128)

__global__ __launch_bounds__(256, 3) void gemm_mfma(const float* __restrict__ feat,
                                                    const unsigned short* __restrict__ wimg,
                                                    const float* __restrict__ bias,
                                                    float* __restrict__ out,
                                                    unsigned short* __restrict__ Y) {
    __shared__ short8 Bls[2048];   // 32 KB

    int tid = threadIdx.x;
    int idx = blockIdx.x;
    int h   = (idx >> 3) & 1;
    int b   = ((idx >> 4) << 3) | (idx & 7);
    if (b >= NB_M) return;

    const short8* wsrc = (const short8*)wimg + h * 2048;
    #pragma unroll
    for (int i = 0; i < 8; ++i)
        Bls[tid + i * 256] = wsrc[tid + i * 256];

    int wave = tid >> 6;
    int lane = tid & 63;
    int m = lane & 31;
    int g = lane >> 5;
    int row0   = b * 128 + wave * 32;
    int row_a  = row0 + m;
    int rclamp = row_a < N_NODES ? row_a : 0;

    short8 fa[8];
    const float* ap = feat + (size_t)rclamp * D + g * 8;
    #pragma unroll
    for (int ks = 0; ks < 8; ++ks) {
        float4 u = *(const float4*)(ap + ks * 16);
        float4 v = *(const float4*)(ap + ks * 16 + 4);
        short8 a;
        a[0] = (short)f2bf(u.x); a[1] = (short)f2bf(u.y);
        a[2] = (short)f2bf(u.z); a[3] = (short)f2bf(u.w);
        a[4] = (short)f2bf(v.x); a[5] = (short)f2bf(v.y);
        a[6] = (short)f2bf(v.z); a[7] = (short)f2bf(v.w);
        fa[ks] = a;
    }
    __syncthreads();

    #pragma unroll
    for (int t4 = 0; t4 < 4; ++t4) {
        int n = t4 * 32 + m;
        floatx16 acc = {0,0,0,0, 0,0,0,0, 0,0,0,0, 0,0,0,0};
        #pragma unroll
        for (int ks = 0; ks < 8; ++ks) {
            short8 bb = Bls[(ks * 2 + g) * 128 + n];
            acc = __builtin_amdgcn_mfma_f32_32x32x16_bf16(fa[ks], bb, acc, 0, 0, 0);
        }
        if (h == 0) {
            float bv = bias[n];
            #pragma unroll
            for (int r = 0; r < 16; ++r) {
                int row = row0 + (r & 3) + 8 * (r >> 2) + 4 * g;
                if (row < N_NODES) out[(size_t)row * D + n] = acc[r] + bv;
            }
        } else {
            #pragma unroll
            for (int r = 0; r < 16; ++r) {
                int row = row0 + (r & 3) + 8 * (r >> 2) + 4 * g;
                if (row < N_NODES) Y[(size_t)row * D + n] = f2bf(acc[r]);
            }
        }
    }
}

// ---------------------------------------------------------------------------
// Kernel 3: out[n,:] += sum_e affine[e] * Y[src[e],:]
// One wave per node, quarter-wave edge parallelism: quarter g owns edge
// parity, lane owns 8 features (uint4 = 16B bf16). Unroll x2 -> 8 edges in
// flight per wave. shfl_xor(16/32) reduce; quarter 0 does float4 RMW on out.
// ---------------------------------------------------------------------------
__global__ __launch_bounds__(256) void agg_add(const unsigned short* __restrict__ Y,
                                               const float* __restrict__ affine,
                                               const int* __restrict__ src,
                                               const int* __restrict__ rowptr,
                                               float* __restrict__ out) {
    int wave = threadIdx.x >> 6;
    int lane = threadIdx.x & 63;
    int n = blockIdx.x * 4 + wave;
    if (n >= N_NODES) return;
    int lo = rowptr[n], hi = rowptr[n + 1];
    int g  = lane >> 4;             // quarter 0..3 = edge slot
    int jj = (lane & 15) << 3;      // feature offset (ushorts): 0..120

    float acc[8] = {0,0,0,0,0,0,0,0};
    const unsigned short* Yj = Y + jj;

    int e = lo;
    for (; e + 8 <= hi; e += 8) {
        int i0 = e + g,  i1 = e + 4 + g;
        int s0 = src[i0];  float w0 = affine[i0];
        int s1 = src[i1];  float w1 = affine[i1];
        uint4 p0 = *(const uint4*)(Yj + (size_t)s0 * D);
        uint4 p1 = *(const uint4*)(Yj + (size_t)s1 * D);
        acc[0] += bflo(p0.x) * w0;  acc[1] += bfhi(p0.x) * w0;
        acc[2] += bflo(p0.y) * w0;  acc[3] += bfhi(p0.y) * w0;
        acc[4] += bflo(p0.z) * w0;  acc[5] += bfhi(p0.z) * w0;
        acc[6] += bflo(p0.w) * w0;  acc[7] += bfhi(p0.w) * w0;
        acc[0] += bflo(p1.x) * w1;  acc[1] += bfhi(p1.x) * w1;
        acc[2] += bflo(p1.y) * w1;  acc[3] += bfhi(p1.y) * w1;
        acc[4] += bflo(p1.z) * w1;  acc[5] += bfhi(p1.z) * w1;
        acc[6] += bflo(p1.w) * w1;  acc[7] += bfhi(p1.w) * w1;
    }
    for (; e < hi; e += 4) {        // predicated tail, up to 7 edges
        int  i = e + g;
        bool v = i < hi;
        int   s = src[v ? i : lo];
        float w = v ? affine[i] : 0.f;
        uint4 p = *(const uint4*)(Yj + (size_t)s * D);
        acc[0] += bflo(p.x) * w;  acc[1] += bfhi(p.x) * w;
        acc[2] += bflo(p.y) * w;  acc[3] += bfhi(p.y) * w;
        acc[4] += bflo(p.z) * w;  acc[5] += bfhi(p.z) * w;
        acc[6] += bflo(p.w) * w;  acc[7] += bfhi(p.w) * w;
    }

    #pragma unroll
    for (int r = 0; r < 8; ++r) {
        acc[r] += __shfl_xor(acc[r], 16);
        acc[r] += __shfl_xor(acc[r], 32);
    }

    if (g == 0) {
        float* op = out + (size_t)n * D + jj;
        float4 z0 = *(const float4*)op;
        float4 z1 = *(const float4*)(op + 4);
        z0.x += acc[0]; z0.y += acc[1]; z0.z += acc[2]; z0.w += acc[3];
        z1.x += acc[4]; z1.y += acc[5]; z1.z += acc[6]; z1.w += acc[7];
        *(float4*)op       = z0;
        *(float4*)(op + 4) = z1;
    }
}

// ---------------------------------------------------------------------------
extern "C" void kernel_launch(void* const* d_in, const int* in_sizes, int n_in,
                              void* d_out, int out_size, void* d_ws, size_t ws_size,
                              hipStream_t stream) {
    const float* feat   = (const float*)d_in[0];
    const float* affine = (const float*)d_in[1];
    const int*   src    = (const int*)  d_in[2];
    const int*   dst    = (const int*)  d_in[3];
    const float* W      = (const float*)d_in[4];
    const float* bias   = (const float*)d_in[5];
    float*       out    = (float*)d_out;

    // ws: wimg (64 KB) @0; rowptr (200 KB) @64K; Y (12.8 MB bf16) @260 KB.
    unsigned short* wimg   = (unsigned short*)d_ws;
    int*            rowptr = (int*)((char*)d_ws + 65536);
    unsigned short* Y      = (unsigned short*)((char*)d_ws + 266240);

    prep_kernel<<<196, 256, 0, stream>>>(dst, W, rowptr, wimg);
    // 2*NB_M blocks, padded to a multiple of 16 for the (b,h) swizzle.
    int gemm_blocks = ((2 * NB_M + 15) / 16) * 16;
    gemm_mfma<<<gemm_blocks, 256, 0, stream>>>(feat, wimg, bias, out, Y);
    agg_add<<<(N_NODES + 3) / 4, 256, 0, stream>>>(Y, affine, src, rowptr, out);
}

// Round 5
// 135.406 us; speedup vs baseline: 1.4190x; 1.0178x over previous
//
#include <hip/hip_runtime.h>

#define N_NODES 50000
#define E_EDGES 625000
#define D 128

typedef __attribute__((ext_vector_type(8)))  short  short8;
typedef __attribute__((ext_vector_type(16))) float  floatx16;

static __device__ inline unsigned short f2bf(float f) {
    union { float f; unsigned u; } v; v.f = f;
    unsigned r = v.u + 0x7FFFu + ((v.u >> 16) & 1u);   // RNE
    return (unsigned short)(r >> 16);
}
static __device__ inline float bflo(unsigned p) { return __uint_as_float(p << 16); }
static __device__ inline float bfhi(unsigned p) { return __uint_as_float(p & 0xFFFF0000u); }

// ---------------------------------------------------------------------------
// Kernel 1 (prep): rowptr via binary search on sorted dst; bf16 W image in
// final LDS layout (slot t = h*2048 + c*128 + n holds W[h*128+c*8+j][n]);
// zipped per-edge metadata meta[e] = {src[e], bits(affine[e])}.
// ---------------------------------------------------------------------------
__global__ __launch_bounds__(256) void prep_kernel(const int* __restrict__ dst,
                                                   const float* __restrict__ W,
                                                   const int* __restrict__ src,
                                                   const float* __restrict__ affine,
                                                   int* __restrict__ rowptr,
                                                   unsigned short* __restrict__ wimg,
                                                   uint2* __restrict__ meta) {
    int t = blockIdx.x * 256 + threadIdx.x;
    if (t <= N_NODES) {
        int lo = 0, hi = E_EDGES;
        while (lo < hi) {
            int mid = (lo + hi) >> 1;
            if (dst[mid] < t) lo = mid + 1; else hi = mid;
        }
        rowptr[t] = lo;
    }
    if (t < 4096) {
        int n = t & 127;
        int c = (t >> 7) & 15;
        int h = t >> 11;
        int krow = h * 128 + c * 8;
        short8 v;
        #pragma unroll
        for (int j = 0; j < 8; ++j)
            v[j] = (short)f2bf(W[(size_t)(krow + j) * D + n]);
        *((short8*)wimg + t) = v;
    }
    if (t < E_EDGES) {
        uint2 m;
        m.x = (unsigned)src[t];
        m.y = __float_as_uint(affine[t]);
        meta[t] = m;
    }
}

// ---------------------------------------------------------------------------
// Kernel 2: Z = feat @ [W1 | W2] with 32x32x16 bf16 MFMA.
// h selects W1 (writes out, +bias) or W2 (writes Y bf16). XCD-pairing swizzle
// keeps the (b,h) pair on one XCD so feat rows hit its L2.
// ---------------------------------------------------------------------------
#define NB_M 391   // ceil(N/128)

__global__ __launch_bounds__(256, 3) void gemm_mfma(const float* __restrict__ feat,
                                                    const unsigned short* __restrict__ wimg,
                                                    const float* __restrict__ bias,
                                                    float* __restrict__ out,
                                                    unsigned short* __restrict__ Y) {
    __shared__ short8 Bls[2048];   // 32 KB

    int tid = threadIdx.x;
    int idx = blockIdx.x;
    int h   = (idx >> 3) & 1;
    int b   = ((idx >> 4) << 3) | (idx & 7);
    if (b >= NB_M) return;

    const short8* wsrc = (const short8*)wimg + h * 2048;
    #pragma unroll
    for (int i = 0; i < 8; ++i)
        Bls[tid + i * 256] = wsrc[tid + i * 256];

    int wave = tid >> 6;
    int lane = tid & 63;
    int m = lane & 31;
    int g = lane >> 5;
    int row0   = b * 128 + wave * 32;
    int row_a  = row0 + m;
    int rclamp = row_a < N_NODES ? row_a : 0;

    short8 fa[8];
    const float* ap = feat + (size_t)rclamp * D + g * 8;
    #pragma unroll
    for (int ks = 0; ks < 8; ++ks) {
        float4 u = *(const float4*)(ap + ks * 16);
        float4 v = *(const float4*)(ap + ks * 16 + 4);
        short8 a;
        a[0] = (short)f2bf(u.x); a[1] = (short)f2bf(u.y);
        a[2] = (short)f2bf(u.z); a[3] = (short)f2bf(u.w);
        a[4] = (short)f2bf(v.x); a[5] = (short)f2bf(v.y);
        a[6] = (short)f2bf(v.z); a[7] = (short)f2bf(v.w);
        fa[ks] = a;
    }
    __syncthreads();

    #pragma unroll
    for (int t4 = 0; t4 < 4; ++t4) {
        int n = t4 * 32 + m;
        floatx16 acc = {0,0,0,0, 0,0,0,0, 0,0,0,0, 0,0,0,0};
        #pragma unroll
        for (int ks = 0; ks < 8; ++ks) {
            short8 bb = Bls[(ks * 2 + g) * 128 + n];
            acc = __builtin_amdgcn_mfma_f32_32x32x16_bf16(fa[ks], bb, acc, 0, 0, 0);
        }
        if (h == 0) {
            float bv = bias[n];
            #pragma unroll
            for (int r = 0; r < 16; ++r) {
                int row = row0 + (r & 3) + 8 * (r >> 2) + 4 * g;
                if (row < N_NODES) out[(size_t)row * D + n] = acc[r] + bv;
            }
        } else {
            #pragma unroll
            for (int r = 0; r < 16; ++r) {
                int row = row0 + (r & 3) + 8 * (r >> 2) + 4 * g;
                if (row < N_NODES) Y[(size_t)row * D + n] = f2bf(acc[r]);
            }
        }
    }
}

// ---------------------------------------------------------------------------
// Kernel 3: out[n,:] += sum_e affine[e] * Y[src[e],:]
// One wave per node; quarter g owns edge slot, lane owns 8 features (uint4).
// 16 edges in flight per round (4 per lane), fully predicated: ~87% of nodes
// (deg<=16) finish in ONE metadata window + ONE gather window.
// ---------------------------------------------------------------------------
__global__ __launch_bounds__(256) void agg_add(const unsigned short* __restrict__ Y,
                                               const uint2* __restrict__ meta,
                                               const int* __restrict__ rowptr,
                                               float* __restrict__ out) {
    int wave = threadIdx.x >> 6;
    int lane = threadIdx.x & 63;
    int n = blockIdx.x * 4 + wave;
    if (n >= N_NODES) return;
    int lo = rowptr[n], hi = rowptr[n + 1];
    int g  = lane >> 4;             // quarter = edge slot
    int jj = (lane & 15) << 3;      // feature offset (ushorts)
    const unsigned short* Yj = Y + jj;

    float acc[8] = {0,0,0,0,0,0,0,0};

    for (int e0 = lo; e0 < hi; e0 += 16) {
        // metadata: 4 independent 8B loads (staircased with gathers below)
        uint2 md[4];
        #pragma unroll
        for (int u = 0; u < 4; ++u) {
            int i = e0 + u * 4 + g;
            md[u] = meta[i < hi ? i : lo];
        }
        float w[4];
        uint4 p[4];
        #pragma unroll
        for (int u = 0; u < 4; ++u) {
            int i = e0 + u * 4 + g;
            w[u] = (i < hi) ? __uint_as_float(md[u].y) : 0.f;
            p[u] = *(const uint4*)(Yj + (size_t)md[u].x * D);
        }
        #pragma unroll
        for (int u = 0; u < 4; ++u) {
            acc[0] += bflo(p[u].x) * w[u];  acc[1] += bfhi(p[u].x) * w[u];
            acc[2] += bflo(p[u].y) * w[u];  acc[3] += bfhi(p[u].y) * w[u];
            acc[4] += bflo(p[u].z) * w[u];  acc[5] += bfhi(p[u].z) * w[u];
            acc[6] += bflo(p[u].w) * w[u];  acc[7] += bfhi(p[u].w) * w[u];
        }
    }

    #pragma unroll
    for (int r = 0; r < 8; ++r) {
        acc[r] += __shfl_xor(acc[r], 16);
        acc[r] += __shfl_xor(acc[r], 32);
    }

    if (g == 0) {
        float* op = out + (size_t)n * D + jj;
        float4 z0 = *(const float4*)op;
        float4 z1 = *(const float4*)(op + 4);
        z0.x += acc[0]; z0.y += acc[1]; z0.z += acc[2]; z0.w += acc[3];
        z1.x += acc[4]; z1.y += acc[5]; z1.z += acc[6]; z1.w += acc[7];
        *(float4*)op       = z0;
        *(float4*)(op + 4) = z1;
    }
}

// ---------------------------------------------------------------------------
extern "C" void kernel_launch(void* const* d_in, const int* in_sizes, int n_in,
                              void* d_out, int out_size, void* d_ws, size_t ws_size,
                              hipStream_t stream) {
    const float* feat   = (const float*)d_in[0];
    const float* affine = (const float*)d_in[1];
    const int*   src    = (const int*)  d_in[2];
    const int*   dst    = (const int*)  d_in[3];
    const float* W      = (const float*)d_in[4];
    const float* bias   = (const float*)d_in[5];
    float*       out    = (float*)d_out;

    // ws: wimg 64KB @0; rowptr 200KB @64K; meta 5MB @266240; Y 12.8MB @5267456.
    unsigned short* wimg   = (unsigned short*)d_ws;
    int*            rowptr = (int*)((char*)d_ws + 65536);
    uint2*          meta   = (uint2*)((char*)d_ws + 266240);
    unsigned short* Y      = (unsigned short*)((char*)d_ws + 5267456);

    prep_kernel<<<(E_EDGES + 255) / 256, 256, 0, stream>>>(dst, W, src, affine,
                                                           rowptr, wimg, meta);
    int gemm_blocks = ((2 * NB_M + 15) / 16) * 16;
    gemm_mfma<<<gemm_blocks, 256, 0, stream>>>(feat, wimg, bias, out, Y);
    agg_add<<<(N_NODES + 3) / 4, 256, 0, stream>>>(Y, meta, rowptr, out);
}

// Round 6
// 127.778 us; speedup vs baseline: 1.5037x; 1.0597x over previous
//
#include <hip/hip_runtime.h>

#define N_NODES 50000
#define E_EDGES 625000
#define D 128

typedef __attribute__((ext_vector_type(8)))  short  short8;
typedef __attribute__((ext_vector_type(16))) float  floatx16;

static __device__ inline unsigned short f2bf(float f) {
    union { float f; unsigned u; } v; v.f = f;
    unsigned r = v.u + 0x7FFFu + ((v.u >> 16) & 1u);   // RNE
    return (unsigned short)(r >> 16);
}
static __device__ inline float bflo(unsigned p) { return __uint_as_float(p << 16); }
static __device__ inline float bfhi(unsigned p) { return __uint_as_float(p & 0xFFFF0000u); }

// ---------------------------------------------------------------------------
// Kernel 1 (prep), all edge-parallel / streaming, O(1) load-chain depth:
//  - rowptr: thread t writes rowptr[n]=t for n in (dst[t-1], dst[t]]
//  - meta[e] = {src[e], bits(affine[e])}
//  - bf16 W image in final LDS layout (slot t = h*2048+c*128+n holds
//    W[h*128+c*8+j][n], j=0..7)
// ---------------------------------------------------------------------------
__global__ __launch_bounds__(256) void prep_kernel(const int* __restrict__ dst,
                                                   const float* __restrict__ W,
                                                   const int* __restrict__ src,
                                                   const float* __restrict__ affine,
                                                   int* __restrict__ rowptr,
                                                   unsigned short* __restrict__ wimg,
                                                   uint2* __restrict__ meta) {
    int t = blockIdx.x * 256 + threadIdx.x;
    if (t < E_EDGES) {
        int d1 = dst[t];
        int d0 = (t == 0) ? -1 : dst[t - 1];
        for (int n = d0 + 1; n <= d1; ++n) rowptr[n] = t;
        if (t == E_EDGES - 1)
            for (int n = d1 + 1; n <= N_NODES; ++n) rowptr[n] = E_EDGES;
        uint2 m;
        m.x = (unsigned)src[t];
        m.y = __float_as_uint(affine[t]);
        meta[t] = m;
    }
    if (t < 4096) {
        int n = t & 127;
        int c = (t >> 7) & 15;
        int h = t >> 11;
        int krow = h * 128 + c * 8;
        short8 v;
        #pragma unroll
        for (int j = 0; j < 8; ++j)
            v[j] = (short)f2bf(W[(size_t)(krow + j) * D + n]);
        *((short8*)wimg + t) = v;
    }
}

// ---------------------------------------------------------------------------
// Kernel 2: [Z1b | Y] = bf16(feat @ [W1 | W2]) with 32x32x16 bf16 MFMA.
// h selects the W half; both halves store bf16 (bias deferred to agg).
// XCD-pairing swizzle keeps the (b,h) pair on one XCD for feat L2 reuse.
// ---------------------------------------------------------------------------
#define NB_M 391   // ceil(N/128)

__global__ __launch_bounds__(256, 3) void gemm_mfma(const float* __restrict__ feat,
                                                    const unsigned short* __restrict__ wimg,
                                                    unsigned short* __restrict__ Z1b,
                                                    unsigned short* __restrict__ Y) {
    __shared__ short8 Bls[2048];   // 32 KB

    int tid = threadIdx.x;
    int idx = blockIdx.x;
    int h   = (idx >> 3) & 1;
    int b   = ((idx >> 4) << 3) | (idx & 7);
    if (b >= NB_M) return;

    const short8* wsrc = (const short8*)wimg + h * 2048;
    #pragma unroll
    for (int i = 0; i < 8; ++i)
        Bls[tid + i * 256] = wsrc[tid + i * 256];

    int wave = tid >> 6;
    int lane = tid & 63;
    int m = lane & 31;
    int g = lane >> 5;
    int row0   = b * 128 + wave * 32;
    int row_a  = row0 + m;
    int rclamp = row_a < N_NODES ? row_a : 0;

    short8 fa[8];
    const float* ap = feat + (size_t)rclamp * D + g * 8;
    #pragma unroll
    for (int ks = 0; ks < 8; ++ks) {
        float4 u = *(const float4*)(ap + ks * 16);
        float4 v = *(const float4*)(ap + ks * 16 + 4);
        short8 a;
        a[0] = (short)f2bf(u.x); a[1] = (short)f2bf(u.y);
        a[2] = (short)f2bf(u.z); a[3] = (short)f2bf(u.w);
        a[4] = (short)f2bf(v.x); a[5] = (short)f2bf(v.y);
        a[6] = (short)f2bf(v.z); a[7] = (short)f2bf(v.w);
        fa[ks] = a;
    }
    __syncthreads();

    unsigned short* dstbuf = h ? Y : Z1b;

    #pragma unroll
    for (int t4 = 0; t4 < 4; ++t4) {
        int n = t4 * 32 + m;
        floatx16 acc = {0,0,0,0, 0,0,0,0, 0,0,0,0, 0,0,0,0};
        #pragma unroll
        for (int ks = 0; ks < 8; ++ks) {
            short8 bb = Bls[(ks * 2 + g) * 128 + n];
            acc = __builtin_amdgcn_mfma_f32_32x32x16_bf16(fa[ks], bb, acc, 0, 0, 0);
        }
        // D layout: col = lane&31, row = (reg&3) + 8*(reg>>2) + 4*g
        #pragma unroll
        for (int r = 0; r < 16; ++r) {
            int row = row0 + (r & 3) + 8 * (r >> 2) + 4 * g;
            if (row < N_NODES) dstbuf[(size_t)row * D + n] = f2bf(acc[r]);
        }
    }
}

// ---------------------------------------------------------------------------
// Kernel 3: out[n,:] = bf2f(Z1b[n,:]) + bias + sum_e affine[e] * Y[src[e],:]
// One wave per node; quarter g owns edge slot, lane owns 8 features (uint4).
// 16 edges in flight per round, fully predicated. Single fp32 write of out.
// ---------------------------------------------------------------------------
__global__ __launch_bounds__(256) void agg_add(const unsigned short* __restrict__ Y,
                                               const unsigned short* __restrict__ Z1b,
                                               const uint2* __restrict__ meta,
                                               const int* __restrict__ rowptr,
                                               const float* __restrict__ bias,
                                               float* __restrict__ out) {
    int wave = threadIdx.x >> 6;
    int lane = threadIdx.x & 63;
    int n = blockIdx.x * 4 + wave;
    if (n >= N_NODES) return;
    int lo = rowptr[n], hi = rowptr[n + 1];
    int g  = lane >> 4;             // quarter = edge slot
    int jj = (lane & 15) << 3;      // feature offset
    const unsigned short* Yj = Y + jj;

    float acc[8] = {0,0,0,0,0,0,0,0};

    for (int e0 = lo; e0 < hi; e0 += 16) {
        uint2 md[4];
        #pragma unroll
        for (int u = 0; u < 4; ++u) {
            int i = e0 + u * 4 + g;
            md[u] = meta[i < hi ? i : lo];
        }
        float w[4];
        uint4 p[4];
        #pragma unroll
        for (int u = 0; u < 4; ++u) {
            int i = e0 + u * 4 + g;
            w[u] = (i < hi) ? __uint_as_float(md[u].y) : 0.f;
            p[u] = *(const uint4*)(Yj + (size_t)md[u].x * D);
        }
        #pragma unroll
        for (int u = 0; u < 4; ++u) {
            acc[0] += bflo(p[u].x) * w[u];  acc[1] += bfhi(p[u].x) * w[u];
            acc[2] += bflo(p[u].y) * w[u];  acc[3] += bfhi(p[u].y) * w[u];
            acc[4] += bflo(p[u].z) * w[u];  acc[5] += bfhi(p[u].z) * w[u];
            acc[6] += bflo(p[u].w) * w[u];  acc[7] += bfhi(p[u].w) * w[u];
        }
    }

    #pragma unroll
    for (int r = 0; r < 8; ++r) {
        acc[r] += __shfl_xor(acc[r], 16);
        acc[r] += __shfl_xor(acc[r], 32);
    }

    if (g == 0) {
        uint4  z  = *(const uint4*)(Z1b + (size_t)n * D + jj);
        float4 b0 = *(const float4*)(bias + jj);
        float4 b1 = *(const float4*)(bias + jj + 4);
        float* op = out + (size_t)n * D + jj;
        float4 o0, o1;
        o0.x = bflo(z.x) + b0.x + acc[0];  o0.y = bfhi(z.x) + b0.y + acc[1];
        o0.z = bflo(z.y) + b0.z + acc[2];  o0.w = bfhi(z.y) + b0.w + acc[3];
        o1.x = bflo(z.z) + b1.x + acc[4];  o1.y = bfhi(z.z) + b1.y + acc[5];
        o1.z = bflo(z.w) + b1.z + acc[6];  o1.w = bfhi(z.w) + b1.w + acc[7];
        *(float4*)op       = o0;
        *(float4*)(op + 4) = o1;
    }
}

// ---------------------------------------------------------------------------
extern "C" void kernel_launch(void* const* d_in, const int* in_sizes, int n_in,
                              void* d_out, int out_size, void* d_ws, size_t ws_size,
                              hipStream_t stream) {
    const float* feat   = (const float*)d_in[0];
    const float* affine = (const float*)d_in[1];
    const int*   src    = (const int*)  d_in[2];
    const int*   dst    = (const int*)  d_in[3];
    const float* W      = (const float*)d_in[4];
    const float* bias   = (const float*)d_in[5];
    float*       out    = (float*)d_out;

    // ws: wimg 64KB @0; rowptr @64K; meta 5MB @266240; Y 12.8MB @5267456;
    //     Z1b 12.8MB @18067456.
    unsigned short* wimg   = (unsigned short*)d_ws;
    int*            rowptr = (int*)((char*)d_ws + 65536);
    uint2*          meta   = (uint2*)((char*)d_ws + 266240);
    unsigned short* Y      = (unsigned short*)((char*)d_ws + 5267456);
    unsigned short* Z1b    = (unsigned short*)((char*)d_ws + 18067456);

    prep_kernel<<<(E_EDGES + 255) / 256, 256, 0, stream>>>(dst, W, src, affine,
                                                           rowptr, wimg, meta);
    int gemm_blocks = ((2 * NB_M + 15) / 16) * 16;
    gemm_mfma<<<gemm_blocks, 256, 0, stream>>>(feat, wimg, Z1b, Y);
    agg_add<<<(N_NODES + 3) / 4, 256, 0, stream>>>(Y, Z1b, meta, rowptr, bias, out);
}